// Round 4
// baseline (4669.486 us; speedup 1.0000x reference)
//
#include <hip/hip_runtime.h>
#include <cstdint>
#include <cstddef>

// ---------------------------------------------------------------------------
// 2-layer LSTM (B=256, S=1024, V=H=256) + FC + log_softmax, MI355X/gfx950.
//
// Round 4: per-wave epoch-flag exchange protocol (replaces sentinel-spin).
//   Producer: relaxed agent data stores -> s_waitcnt vmcnt(0) (stores acked
//   at coherence point) -> relaxed flag store (t+1). Consumer: spin on 2 flag
//   dwords only, then ONE bulk 8x8B atomic data read. Cuts coherent-request
//   rate ~60x vs per-dword sentinel polling (the round-3 congestion).
//   No sentinels -> no 268MB memsets.
//
// Phases: pack_w x5 -> memset flags (32KB) -> lstm_dual -> fc_lsm.
// Workspace ~271 MB: packed weights | flags | h1 (134MB) | h2 (134MB)
// ---------------------------------------------------------------------------

typedef __attribute__((ext_vector_type(8))) short bf16x8;
typedef __attribute__((ext_vector_type(4))) float f32x4;
typedef unsigned long long ull;

#define DEVFN __device__ __forceinline__

DEVFN unsigned short f2bf(float f) {
  union { float f; unsigned u; } v; v.f = f;
  unsigned r = v.u + 0x7FFFu + ((v.u >> 16) & 1u);   // RNE
  return (unsigned short)(r >> 16);
}
// XOR swizzle inside a [rows][512B] LDS tile: 16B slot ^= (row&7)
DEVFN int swz(int row, int colbyte) {
  return row * 512 + ((((colbyte >> 4) ^ (row & 7)) << 4) | (colbyte & 15));
}
DEVFN float sigm(float x) { return __builtin_amdgcn_rcpf(1.f + __expf(-x)); }
DEVFN float tanhfast(float x) {
  float ax = fabsf(x);
  float e  = __expf(-2.f * ax);
  float t  = (1.f - e) * __builtin_amdgcn_rcpf(1.f + e);
  return copysignf(t, x);
}

DEVFN unsigned aload(const unsigned* p) {
  return __hip_atomic_load(p, __ATOMIC_RELAXED, __HIP_MEMORY_SCOPE_AGENT);
}
DEVFN ull aload64(const ull* p) {
  return __hip_atomic_load(p, __ATOMIC_RELAXED, __HIP_MEMORY_SCOPE_AGENT);
}
DEVFN void astore(unsigned* p, unsigned v) {
  __hip_atomic_store(p, v, __ATOMIC_RELAXED, __HIP_MEMORY_SCOPE_AGENT);
}

// flag slot for (layer L, m-group, producer WG n, wave w); 64B stride.
DEVFN unsigned* flag_at(unsigned* f, int L, int m, int n, int w) {
  return f + (((((L * 16 + m) * 8) + n) * 2 + w) << 4);
}

// --------------------------------------------------------------------------
// Pack W[col][k] (K=256) into B-fragment tiles:
//   dst[((nt*8+kt)*64+lane)*8 + j] = bf16( W[nt*16+(lane&15)][kt*32+(lane>>4)*8+j] )
// grid = (ncols/16)*8 blocks of 64 threads.
// --------------------------------------------------------------------------
__global__ void pack_w(const float* __restrict__ w, unsigned short* __restrict__ dst) {
  int bid = blockIdx.x;           // nt*8 + kt
  int lane = threadIdx.x;
  int col = (bid >> 3) * 16 + (lane & 15);
  int k0  = (bid & 7) * 32 + (lane >> 4) * 8;
  const float* src = w + (size_t)col * 256 + k0;
  unsigned short* d = dst + ((size_t)bid * 64 + lane) * 8;
#pragma unroll
  for (int j = 0; j < 8; ++j) d[j] = f2bf(src[j]);
}

// --------------------------------------------------------------------------
// Dual-layer persistent LSTM. grid = 256 WGs x 128 thr (2 waves).
//   bid <  128 : layer 0, b = bid      (m = b&15, n = b>>4)
//   bid >= 128 : layer 1, b = bid-128
// bid%8 == m%8 for both halves -> the 16 WGs of an m-group share an XCD
// under the bid%8 placement heuristic (perf only, not correctness).
// Wave w owns unit-tile u16=n*2+w (16 units x all 4 gates); W_ih/W_hh
// fragments register-resident. Exchange: epoch flags per producer wave.
// h layout: [S][256 b][256 u] bf16.
// --------------------------------------------------------------------------
__global__ __launch_bounds__(128, 1) void lstm_dual(
    const float* __restrict__ x,
    const unsigned short* __restrict__ Wih0, const unsigned short* __restrict__ Whh0,
    const float* __restrict__ bih0, const float* __restrict__ bhh0,
    const unsigned short* __restrict__ Wih1, const unsigned short* __restrict__ Whh1,
    const float* __restrict__ bih1, const float* __restrict__ bhh1,
    unsigned short* __restrict__ h1, unsigned short* __restrict__ h2,
    unsigned* __restrict__ flags)
{
  __shared__ char ldsA[8192];   // hh A-tile (h[t-1] of own layer)
  __shared__ char ldsB[8192];   // ih A-tile (x[t] or h1[t])
  const int tid = threadIdx.x;
  const int w = tid >> 6, lane = tid & 63;
  const bool isL1 = blockIdx.x >= 128;
  const int b = isL1 ? (int)blockIdx.x - 128 : (int)blockIdx.x;
  const int m = b & 15, n = b >> 4;
  const int u16 = n * 2 + w;            // unit-tile 0..15
  const int u   = u16 * 16 + (lane & 15);
  const int r0  = (lane >> 4) * 4;      // first of this lane's 4 C rows

  const unsigned short* Wih = isL1 ? Wih1 : Wih0;
  const unsigned short* Whh = isL1 ? Whh1 : Whh0;
  const float* bihp = isL1 ? bih1 : bih0;
  const float* bhhp = isL1 ? bhh1 : bhh0;
  unsigned short* hout = isL1 ? h2 : h1;

  // register-resident weight fragments: nt = g*16 + u16
  bf16x8 bwih[4][8], bwhh[4][8];
#pragma unroll
  for (int g = 0; g < 4; ++g)
#pragma unroll
    for (int kt = 0; kt < 8; ++kt) {
      bwih[g][kt] = *(const bf16x8*)(Wih +
          ((((size_t)(g * 16 + u16)) * 8 + kt) * 64 + lane) * 8);
      bwhh[g][kt] = *(const bf16x8*)(Whh +
          ((((size_t)(g * 16 + u16)) * 8 + kt) * 64 + lane) * 8);
    }

  float bias[4];
#pragma unroll
  for (int g = 0; g < 4; ++g) bias[g] = bihp[g * 256 + u] + bhhp[g * 256 + u];

  float c[4] = {0.f, 0.f, 0.f, 0.f};

  // data-exchange mapping: thread stages row r, unit block [cc*32, cc*32+32)
  // (producer WG cc, both its waves).
  const int r = tid >> 3, cc = tid & 7;
  const int Lown = isL1 ? 1 : 0;
  unsigned* fown = flag_at(flags, Lown, m, n, w);        // this wave's flag
  const unsigned* fh_0 = flag_at(flags, Lown, m, cc, 0); // own-layer h[t-1]
  const unsigned* fh_1 = flag_at(flags, Lown, m, cc, 1);
  const unsigned* fs_0 = flag_at(flags, 0, m, cc, 0);    // L1 only: h1[t]
  const unsigned* fs_1 = flag_at(flags, 0, m, cc, 1);

  if (!isL1) {
    // ---------------- layer 0 ----------------
    float4 vv[8];
    {
      const float4* s = (const float4*)(x + ((size_t)(16 * m + r) * 1024 + 0) * 256 + cc * 32);
#pragma unroll
      for (int j = 0; j < 8; ++j) vv[j] = s[j];
    }

    for (int t = 0; t < 1024; ++t) {
      // stage x[t] (in vv) -> ldsB as bf16
#pragma unroll
      for (int s4 = 0; s4 < 4; ++s4) {
        uint4 o;
        o.x = f2bf(vv[2*s4].x)   | ((unsigned)f2bf(vv[2*s4].y)   << 16);
        o.y = f2bf(vv[2*s4].z)   | ((unsigned)f2bf(vv[2*s4].w)   << 16);
        o.z = f2bf(vv[2*s4+1].x) | ((unsigned)f2bf(vv[2*s4+1].y) << 16);
        o.w = f2bf(vv[2*s4+1].z) | ((unsigned)f2bf(vv[2*s4+1].w) << 16);
        *(uint4*)(&ldsB[swz(r, cc * 64 + s4 * 16)]) = o;
      }
      if (t < 1023) {  // prefetch x[t+1] (done well before end-of-step vmcnt(0))
        const float4* s = (const float4*)(x + ((size_t)(16 * m + r) * 1024 + (t + 1)) * 256 + cc * 32);
#pragma unroll
        for (int j = 0; j < 8; ++j) vv[j] = s[j];
      }
      __syncthreads();                   // bar1: ldsB ready

      f32x4 acc[4];
#pragma unroll
      for (int g = 0; g < 4; ++g) acc[g] = (f32x4){0.f, 0.f, 0.f, 0.f};
#pragma unroll
      for (int kt = 0; kt < 8; ++kt) {   // ih-MFMA (overlaps peer flag wait)
        bf16x8 a = *(const bf16x8*)(&ldsB[swz(lane & 15, kt * 64 + (lane >> 4) * 16)]);
#pragma unroll
        for (int g = 0; g < 4; ++g)
          acc[g] = __builtin_amdgcn_mfma_f32_16x16x32_bf16(a, bwih[g][kt], acc[g], 0, 0, 0);
      }

      if (t > 0) {
        const unsigned tgt = (unsigned)t;          // flag==t  <=>  h[t-1] published
        while (aload(fh_0) < tgt) {}
        while (aload(fh_1) < tgt) {}
        const ull* hs = (const ull*)h1 + ((size_t)(t - 1) * 256 + 16 * m + r) * 64 + cc * 8;
        ull hv[8];
#pragma unroll
        for (int k = 0; k < 8; ++k) hv[k] = aload64(hs + k);
#pragma unroll
        for (int s4 = 0; s4 < 4; ++s4) {
          uint4 o;
          o.x = (unsigned)hv[2*s4];       o.y = (unsigned)(hv[2*s4] >> 32);
          o.z = (unsigned)hv[2*s4+1];     o.w = (unsigned)(hv[2*s4+1] >> 32);
          *(uint4*)(&ldsA[swz(r, cc * 64 + s4 * 16)]) = o;
        }
      }
      __syncthreads();                   // bar2: ldsA ready

      if (t > 0) {
#pragma unroll
        for (int kt = 0; kt < 8; ++kt) { // hh-MFMA
          bf16x8 a = *(const bf16x8*)(&ldsA[swz(lane & 15, kt * 64 + (lane >> 4) * 16)]);
#pragma unroll
          for (int g = 0; g < 4; ++g)
            acc[g] = __builtin_amdgcn_mfma_f32_16x16x32_bf16(a, bwhh[g][kt], acc[g], 0, 0, 0);
        }
      }

      // gates + publish h1[t]
      unsigned myh[4];
#pragma unroll
      for (int q = 0; q < 4; ++q) {
        float ia = acc[0][q] + bias[0];
        float fa = acc[1][q] + bias[1];
        float ga = acc[2][q] + bias[2];
        float oa = acc[3][q] + bias[3];
        c[q] = sigm(fa) * c[q] + sigm(ia) * tanhfast(ga);
        myh[q] = (unsigned)f2bf(sigm(oa) * tanhfast(c[q]));
      }
#pragma unroll
      for (int q = 0; q < 4; ++q) {
        unsigned ov = (unsigned)__shfl_xor((int)myh[q], 1, 64);
        if ((lane & 1) == 0) {
          unsigned word = (myh[q] & 0xFFFFu) | (ov << 16);
          unsigned* hp = (unsigned*)h1 + (((size_t)t * 256 + 16 * m + r0 + q) * 256 + u) / 2;
          astore(hp, word);
        }
      }
      // release: wave's data stores acked at coherence point, THEN flag.
      asm volatile("s_waitcnt vmcnt(0)" ::: "memory");
      if (lane == 0) astore(fown, (unsigned)(t + 1));
    }
  } else {
    // ---------------- layer 1 ----------------
    for (int t = 0; t < 1024; ++t) {
      ull hv2[8];
      if (t > 0) {                       // h2[t-1] (own-layer peers; flags old)
        const unsigned tgt = (unsigned)t;
        while (aload(fh_0) < tgt) {}
        while (aload(fh_1) < tgt) {}
        const ull* hs2 = (const ull*)h2 + ((size_t)(t - 1) * 256 + 16 * m + r) * 64 + cc * 8;
#pragma unroll
        for (int k = 0; k < 8; ++k) hv2[k] = aload64(hs2 + k);
      }
      // h1[t] from layer-0 WGs
      {
        const unsigned tgt = (unsigned)(t + 1);
        while (aload(fs_0) < tgt) {}
        while (aload(fs_1) < tgt) {}
      }
      const ull* hs1 = (const ull*)h1 + ((size_t)t * 256 + 16 * m + r) * 64 + cc * 8;
      ull hv1[8];
#pragma unroll
      for (int k = 0; k < 8; ++k) hv1[k] = aload64(hs1 + k);

      if (t > 0) {
#pragma unroll
        for (int s4 = 0; s4 < 4; ++s4) {
          uint4 o;
          o.x = (unsigned)hv2[2*s4];      o.y = (unsigned)(hv2[2*s4] >> 32);
          o.z = (unsigned)hv2[2*s4+1];    o.w = (unsigned)(hv2[2*s4+1] >> 32);
          *(uint4*)(&ldsA[swz(r, cc * 64 + s4 * 16)]) = o;
        }
      }
      __syncthreads();                   // bar1: ldsA ready

      f32x4 acc[4];
#pragma unroll
      for (int g = 0; g < 4; ++g) acc[g] = (f32x4){0.f, 0.f, 0.f, 0.f};
      if (t > 0) {
#pragma unroll
        for (int kt = 0; kt < 8; ++kt) { // hh-MFMA (covers hv1 flight)
          bf16x8 a = *(const bf16x8*)(&ldsA[swz(lane & 15, kt * 64 + (lane >> 4) * 16)]);
#pragma unroll
          for (int g = 0; g < 4; ++g)
            acc[g] = __builtin_amdgcn_mfma_f32_16x16x32_bf16(a, bwhh[g][kt], acc[g], 0, 0, 0);
        }
      }
      // stage h1[t] -> ldsB
#pragma unroll
      for (int s4 = 0; s4 < 4; ++s4) {
        uint4 o;
        o.x = (unsigned)hv1[2*s4];        o.y = (unsigned)(hv1[2*s4] >> 32);
        o.z = (unsigned)hv1[2*s4+1];      o.w = (unsigned)(hv1[2*s4+1] >> 32);
        *(uint4*)(&ldsB[swz(r, cc * 64 + s4 * 16)]) = o;
      }
      __syncthreads();                   // bar2: ldsB ready

#pragma unroll
      for (int kt = 0; kt < 8; ++kt) {   // ih-MFMA on h1[t]
        bf16x8 a = *(const bf16x8*)(&ldsB[swz(lane & 15, kt * 64 + (lane >> 4) * 16)]);
#pragma unroll
        for (int g = 0; g < 4; ++g)
          acc[g] = __builtin_amdgcn_mfma_f32_16x16x32_bf16(a, bwih[g][kt], acc[g], 0, 0, 0);
      }

      // gates + publish h2[t]
      unsigned myh[4];
#pragma unroll
      for (int q = 0; q < 4; ++q) {
        float ia = acc[0][q] + bias[0];
        float fa = acc[1][q] + bias[1];
        float ga = acc[2][q] + bias[2];
        float oa = acc[3][q] + bias[3];
        c[q] = sigm(fa) * c[q] + sigm(ia) * tanhfast(ga);
        myh[q] = (unsigned)f2bf(sigm(oa) * tanhfast(c[q]));
      }
#pragma unroll
      for (int q = 0; q < 4; ++q) {
        unsigned ov = (unsigned)__shfl_xor((int)myh[q], 1, 64);
        if ((lane & 1) == 0) {
          unsigned word = (myh[q] & 0xFFFFu) | (ov << 16);
          unsigned* hp = (unsigned*)h2 + (((size_t)t * 256 + 16 * m + r0 + q) * 256 + u) / 2;
          astore(hp, word);
        }
      }
      asm volatile("s_waitcnt vmcnt(0)" ::: "memory");
      if (lane == 0) astore(fown, (unsigned)(t + 1));
    }
  }
}

// --------------------------------------------------------------------------
// logits = h2 @ fc_w^T + fc_b; out = logits - logsumexp(logits) (rows of 256).
// Block = 256 thr (4 waves); tile = 64 rows (fixed t, 64 b's) x 256 cols.
// grid = 4096 (t = bid>>2, b0 = (bid&3)*64).
// --------------------------------------------------------------------------
__global__ __launch_bounds__(256, 1) void fc_lsm(
    const unsigned short* __restrict__ h2,
    const unsigned short* __restrict__ Bp,
    const float* __restrict__ fcb,
    float* __restrict__ out)
{
  const int tid = threadIdx.x;
  const int wid = tid >> 6, lane = tid & 63;
  const int t = blockIdx.x >> 2, b0 = (blockIdx.x & 3) * 64;

  f32x4 acc[16];
#pragma unroll
  for (int nt = 0; nt < 16; ++nt) acc[nt] = (f32x4){0.f, 0.f, 0.f, 0.f};

#pragma unroll
  for (int kt = 0; kt < 8; ++kt) {
    bf16x8 a = *(const bf16x8*)(h2 +
        (((size_t)t * 256 + b0 + wid * 16 + (lane & 15)) * 256 +
         kt * 32 + (lane >> 4) * 8));
#pragma unroll
    for (int nt = 0; nt < 16; ++nt) {
      bf16x8 b = *(const bf16x8*)(Bp + (((size_t)nt * 8 + kt) * 64 + lane) * 8);
      acc[nt] = __builtin_amdgcn_mfma_f32_16x16x32_bf16(a, b, acc[nt], 0, 0, 0);
    }
  }
#pragma unroll
  for (int nt = 0; nt < 16; ++nt) {
    float bias = fcb[nt * 16 + (lane & 15)];
#pragma unroll
    for (int q = 0; q < 4; ++q) acc[nt][q] += bias;
  }

  float mx[4] = {-1e30f, -1e30f, -1e30f, -1e30f};
#pragma unroll
  for (int nt = 0; nt < 16; ++nt)
#pragma unroll
    for (int q = 0; q < 4; ++q) mx[q] = fmaxf(mx[q], acc[nt][q]);
#pragma unroll
  for (int d = 1; d < 16; d <<= 1)
#pragma unroll
    for (int q = 0; q < 4; ++q) mx[q] = fmaxf(mx[q], __shfl_xor(mx[q], d, 64));

  float sm[4] = {0.f, 0.f, 0.f, 0.f};
#pragma unroll
  for (int nt = 0; nt < 16; ++nt)
#pragma unroll
    for (int q = 0; q < 4; ++q) sm[q] += __expf(acc[nt][q] - mx[q]);
#pragma unroll
  for (int d = 1; d < 16; d <<= 1)
#pragma unroll
    for (int q = 0; q < 4; ++q) sm[q] += __shfl_xor(sm[q], d, 64);

  float lse[4];
#pragma unroll
  for (int q = 0; q < 4; ++q) lse[q] = mx[q] + __logf(sm[q]);

#pragma unroll
  for (int nt = 0; nt < 16; ++nt) {
#pragma unroll
    for (int q = 0; q < 4; ++q) {
      int b = b0 + wid * 16 + (lane >> 4) * 4 + q;
      out[((size_t)b * 1024 + t) * 256 + nt * 16 + (lane & 15)] = acc[nt][q] - lse[q];
    }
  }
}

// Unambiguous marker if workspace is too small.
__global__ void fill_marker(float* out, size_t nvals) {
  size_t i = (size_t)blockIdx.x * blockDim.x + threadIdx.x;
  if (i < nvals) out[i] = -7777.0f;
}

// --------------------------------------------------------------------------
extern "C" void kernel_launch(void* const* d_in, const int* in_sizes, int n_in,
                              void* d_out, int out_size, void* d_ws, size_t ws_size,
                              hipStream_t stream)
{
  (void)in_sizes; (void)n_in;
  const float* x    = (const float*)d_in[0];
  const float* wih0 = (const float*)d_in[1];
  const float* whh0 = (const float*)d_in[2];
  const float* bih0 = (const float*)d_in[3];
  const float* bhh0 = (const float*)d_in[4];
  const float* wih1 = (const float*)d_in[5];
  const float* whh1 = (const float*)d_in[6];
  const float* bih1 = (const float*)d_in[7];
  const float* bhh1 = (const float*)d_in[8];
  const float* fcw  = (const float*)d_in[9];
  const float* fcb  = (const float*)d_in[10];
  float* out = (float*)d_out;

  // workspace layout (bytes)
  const size_t o_wp0i = 0;
  const size_t o_wp0h = o_wp0i + 524288;
  const size_t o_wp1i = o_wp0h + 524288;
  const size_t o_wp1h = o_wp1i + 524288;
  const size_t o_fcp  = o_wp1h + 524288;        // 131072
  const size_t o_flg  = o_fcp  + 131072;        // 32768 (2x16x8x2 flags, 64B stride)
  const size_t o_h1   = o_flg  + 32768;         // 134217728
  const size_t o_h2   = o_h1   + 134217728;     // 134217728
  const size_t need   = o_h2   + 134217728;     // ~271 MB

  if (ws_size < need) {
    size_t nv = (size_t)out_size;
    fill_marker<<<(unsigned)((nv + 1023) / 1024), 1024, 0, stream>>>(out, nv);
    return;
  }

  char* ws = (char*)d_ws;
  unsigned short* wp0i = (unsigned short*)(ws + o_wp0i);
  unsigned short* wp0h = (unsigned short*)(ws + o_wp0h);
  unsigned short* wp1i = (unsigned short*)(ws + o_wp1i);
  unsigned short* wp1h = (unsigned short*)(ws + o_wp1h);
  unsigned short* fcp  = (unsigned short*)(ws + o_fcp);
  unsigned*       flg  = (unsigned*)(ws + o_flg);
  unsigned short* h1   = (unsigned short*)(ws + o_h1);
  unsigned short* h2   = (unsigned short*)(ws + o_h2);

  pack_w<<<512, 64, 0, stream>>>(wih0, wp0i);
  pack_w<<<512, 64, 0, stream>>>(whh0, wp0h);
  pack_w<<<512, 64, 0, stream>>>(wih1, wp1i);
  pack_w<<<512, 64, 0, stream>>>(whh1, wp1h);
  pack_w<<<128, 64, 0, stream>>>(fcw,  fcp);

  hipMemsetAsync(flg, 0, 32768, stream);   // epoch flags = 0

  lstm_dual<<<256, 128, 0, stream>>>(x, wp0i, wp0h, bih0, bhh0,
                                     wp1i, wp1h, bih1, bhh1, h1, h2, flg);

  fc_lsm<<<4096, 256, 0, stream>>>(h2, fcp, fcb, out);
}